// Round 14
// baseline (417.689 us; speedup 1.0000x reference)
//
#include <hip/hip_runtime.h>
#include <hip/hip_bf16.h>

constexpr int NN = 50000;
constexpr int EE = 200000;
constexpr int SB = (NN + 255) / 256;    // 196 scan blocks per array
constexpr int CB = (NN * 16 + 255) / 256; // 3125 cast blocks
typedef __bf16 bf16x8 __attribute__((ext_vector_type(8)));
typedef float f32x4 __attribute__((ext_vector_type(4)));
typedef unsigned u32x4 __attribute__((ext_vector_type(4)));   // plain vec for nontemporal

__device__ __forceinline__ float b2f(unsigned short s) {
    union { unsigned u; float f; } c; c.u = ((unsigned)s) << 16; return c.f;
}
__device__ __forceinline__ unsigned short bfbits(float f) {
    union { __bf16 b; unsigned short u; } c; c.b = (__bf16)f; return c.u;
}
__device__ __forceinline__ unsigned pkbf(float lo, float hi) {
    return ((unsigned)bfbits(hi) << 16) | bfbits(lo);
}
__device__ __forceinline__ float xv(const void* p, long i, int f32m) {
    return f32m ? ((const float*)p)[i] : b2f(((const unsigned short*)p)[i]);
}
__device__ __forceinline__ int iv(const int* p, int i, int i64m) {
    return i64m ? p[2 * i] : p[i];
}

// parallel dtype sniff (1024 threads)
__global__ void k_detect(const unsigned short* x16, const int* c32, int* flg) {
    __shared__ int sf, si;
    int t = threadIdx.x;
    if (t == 0) { sf = 0; si = 1; }
    __syncthreads();
    for (int i = t; i < 16384; i += 1024)
        if (((x16[i] >> 7) & 0xFF) == 0xFF) sf = 1;
    if (t < 64)
        if (c32[2 * t + 1] != 0) si = 0;
    __syncthreads();
    if (t == 0) { flg[0] = sf; flg[1] = si; }
}

// merged: cast x->xb (blocks 0..CB-1) + W-fragment packing (last 16 blocks)
__global__ void k_prep(const void* x, unsigned short* xb,
                       const void* W1, const void* W2,
                       unsigned short* Wf1, unsigned short* Wf2, const int* flg) {
    int g = blockIdx.x, f32m = flg[0];
    if (g < CB) {
        int i = g * 256 + threadIdx.x;
        if (i >= NN * 16) return;
        if (f32m) {
            const float4* xp = (const float4*)x + (size_t)i * 2;
            float4 u = xp[0], v = xp[1];
            uint4 o;
            o.x = pkbf(u.x, u.y); o.y = pkbf(u.z, u.w);
            o.z = pkbf(v.x, v.y); o.w = pkbf(v.z, v.w);
            ((uint4*)xb)[i] = o;
        } else {
            ((uint4*)xb)[i] = ((const uint4*)x)[i];
        }
    } else {
        int gg = g - CB;   // 0..15
        const void* W = (gg < 8) ? W1 : W2;
        unsigned short* Wf = (gg < 8) ? Wf1 : Wf2;
        int chunk = (gg & 7) * 256 + threadIdx.x;
        int l = chunk & 63, c = (chunk >> 6) & 3, t = chunk >> 8;
        int n = t * 16 + (l & 15), k0 = c * 32 + ((l >> 4) * 8);
        for (int j = 0; j < 8; j++)
            Wf[chunk * 8 + j] = bfbits(xv(W, (long)(k0 + j) * 128 + n, f32m));
    }
}

// both histograms: counts[0..NN) by col1, counts[NN..2NN) by col0
__global__ void k_hist2(const int* col0, const int* col1, int* counts, const int* flg) {
    int e = blockIdx.x * 256 + threadIdx.x;
    if (e >= EE) return;
    int i64m = flg[1];
    atomicAdd(&counts[iv(col1, e, i64m)], 1);
    atomicAdd(&counts[NN + iv(col0, e, i64m)], 1);
}

// scan stage 1 over both arrays (grid 2*SB)
__global__ void k_scan1(const int* counts, int* bsum) {
    __shared__ int sh[256];
    int b = blockIdx.x, t = threadIdx.x;
    int aid = (b >= SB) ? 1 : 0;
    int b2 = b - aid * SB;
    int idx = b2 * 256 + t;
    sh[t] = (idx < NN) ? counts[aid * NN + idx] : 0;
    __syncthreads();
    for (int off = 128; off > 0; off >>= 1) {
        if (t < off) sh[t] += sh[t + off];
        __syncthreads();
    }
    if (t == 0) bsum[b] = sh[0];
}

// scan stage 2: aid 0 -> row_ptr + cursor1 (col1 CSR); aid 1 -> cursor0 (col0 CSR)
__global__ void k_scan2(const int* counts, const int* bsum,
                        int* row_ptr, int* cursor1, int* cursor0) {
    __shared__ int sh[256];
    __shared__ int base_s;
    int b = blockIdx.x, t = threadIdx.x;
    int aid = (b >= SB) ? 1 : 0;
    int b2 = b - aid * SB;
    sh[t] = (t < b2) ? bsum[aid * SB + t] : 0;
    __syncthreads();
    for (int off = 128; off > 0; off >>= 1) {
        if (t < off) sh[t] += sh[t + off];
        __syncthreads();
    }
    if (t == 0) base_s = sh[0];
    __syncthreads();
    int idx = b2 * 256 + t;
    int v = (idx < NN) ? counts[aid * NN + idx] : 0;
    sh[t] = v;
    __syncthreads();
    for (int off = 1; off < 256; off <<= 1) {
        int add = (t >= off) ? sh[t - off] : 0;
        __syncthreads();
        sh[t] += add;
        __syncthreads();
    }
    int ex = base_s + sh[t] - v;
    if (idx < NN) {
        if (aid == 0) { row_ptr[idx] = ex; cursor1[idx] = ex; }
        else cursor0[idx] = ex;
    }
    if (aid == 0 && idx == NN - 1) row_ptr[NN] = ex + v;
}

// both CSR scatters in one pass.
// col1 slot p1: aux[p1] = col0 | selfloop<<31   (for gath's message lists)
// col0 slot q : a0[q]=col0, b0[q]=col1, p0[q]=p1 (edge's col1-position)
__global__ void k_cscatter2(const int* col0, const int* col1,
                            int* cursor1, int* cursor0,
                            unsigned* aux, int* a0, int* b0, int* p0, const int* flg) {
    int e = blockIdx.x * 256 + threadIdx.x;
    if (e >= EE) return;
    int i64m = flg[1];
    int a = iv(col0, e, i64m), b = iv(col1, e, i64m);
    int p1 = atomicAdd(&cursor1[b], 1);
    aux[p1] = (unsigned)a | (a == b ? 0x80000000u : 0u);
    int q = atomicAdd(&cursor0[a], 1);
    a0[q] = a; b0[q] = b; p0[q] = p1;
}

// per-node aggregation over col1-CSR (one wave per node, lane = 2 cols).
// mode 1: T1[n] = 0.5*xb[n] + sum relu(0.5*xb[a] + 1.5*xb[n])   (xb gather)
// mode 2: S2[n] =             sum relu(lgX_c1[p] + xb[n])       (SEQUENTIAL)
__global__ void k_gath(const unsigned short* xb, const unsigned short* lgX,
                       const int* row_ptr, const unsigned* aux,
                       unsigned short* S, int mode) {
    int n = blockIdx.x * 4 + (threadIdx.x >> 6);
    if (n >= NN) return;
    int l = threadIdx.x & 63, k0 = l * 2;
    int lo = row_ptr[n], hi = row_ptr[n + 1];
    unsigned un = *(const unsigned*)(xb + (size_t)n * 128 + k0);
    float xn0 = b2f((unsigned short)un), xn1 = b2f((unsigned short)(un >> 16));
    float a0_ = 0.0f, a1_ = 0.0f;
    if (mode == 1) {
        for (int p = lo; p < hi; p++) {
            unsigned av = aux[p];
            if (av & 0x80000000u) continue;
            unsigned u = *(const unsigned*)(xb + (size_t)av * 128 + k0);
            a0_ += fmaxf(0.5f * b2f((unsigned short)u) + 1.5f * xn0, 0.0f);
            a1_ += fmaxf(0.5f * b2f((unsigned short)(u >> 16)) + 1.5f * xn1, 0.0f);
        }
        a0_ += 0.5f * xn0; a1_ += 0.5f * xn1;   // fold 0.5*xb[n] into T1
    } else {
        for (int p = lo; p < hi; p++) {
            if (aux[p] & 0x80000000u) continue;
            unsigned u = *(const unsigned*)(lgX + (size_t)p * 128 + k0);
            a0_ += fmaxf(b2f((unsigned short)u) + xn0, 0.0f);
            a1_ += fmaxf(b2f((unsigned short)(u >> 16)) + xn1, 0.0f);
        }
    }
    *(unsigned*)(S + (size_t)n * 128 + k0) = pkbf(a0_, a1_);
}

// Fused 2-layer MLP in COL0-GROUPED order, wave = 16 entries.
// PHASE-LOCKED: __syncthreads before each GEMM keeps the 4 waves' identical
// Wf streams aligned so 3 of 4 waves hit L1 (Wf = 64KB/block, L1 = 32KB).
// mode 1: A[q] = T1[a0[q]] + 0.5*xb[b0[q]]; stores lgX to col0-order + col1-scatter.
// mode 2: A[q] = lgX_c0[q] + S2[a0[q]]; stores only col1-scatter.
__global__ __launch_bounds__(256, 8)
void k_fused(const unsigned short* TS, const unsigned short* Aseq,
             const unsigned short* xb, const int* a0, const int* b0, const int* p0,
             const void* bias1, const void* bias2,
             const unsigned short* Wf1, const unsigned short* Wf2,
             unsigned short* Oc0, unsigned short* Oc1, const int* flg, int mode) {
    __shared__ unsigned short Lds[8192];   // 4 waves x 4KB
    int f32m = flg[0];
    int tid = threadIdx.x;
    int w = tid >> 6, l = tid & 63;
    int lq = l >> 4, ln = l & 15;
    int e0 = blockIdx.x * 64 + w * 16;     // wave's 16 col0-slots (EE % 64 == 0)
    unsigned short* W_ = Lds + w * 2048;

    // ---- stage A-frag in registers
    int q = e0 + ln;
    int aN = a0[q];
    int bN = (mode == 1) ? b0[q] : 0;
    bf16x8 af[4];
    for (int c = 0; c < 4; c++) {
        int k0 = c * 32 + lq * 8;
        uint4 tvv = *(const uint4*)(TS + (size_t)aN * 128 + k0);
        const unsigned short* tp = (const unsigned short*)&tvv;
        if (mode == 1) {
            uint4 xbv = *(const uint4*)(xb + (size_t)bN * 128 + k0);
            const unsigned short* xc = (const unsigned short*)&xbv;
            for (int j = 0; j < 8; j++)
                af[c][j] = (__bf16)(b2f(tp[j]) + 0.5f * b2f(xc[j]));
        } else {
            uint4 av = *(const uint4*)(Aseq + (size_t)q * 128 + k0);
            const unsigned short* ap = (const unsigned short*)&av;
            for (int j = 0; j < 8; j++)
                af[c][j] = (__bf16)(b2f(ap[j]) + b2f(tp[j]));
        }
    }

    __syncthreads();   // phase-lock waves -> shared Wf1 stream hits L1

    // ---- GEMM1: rows 16, cols 128
    f32x4 acc[8];
    for (int j = 0; j < 8; j++)
        for (int r = 0; r < 4; r++) acc[j][r] = 0.0f;
    for (int c = 0; c < 4; c++) {
        for (int j = 0; j < 8; j++) {
            bf16x8 bf = *(const bf16x8*)(Wf1 + (size_t)(((j * 4 + c) * 64 + l) * 8));
            acc[j] = __builtin_amdgcn_mfma_f32_16x16x32_bf16(af[c], bf, acc[j], 0, 0, 0);
        }
    }

    // ---- H = relu(C1+b1) -> LDS in A-frag order (cross-lane transpose)
    for (int j = 0; j < 8; j++) {
        int n = j * 16 + ln;
        float bv = xv(bias1, n, f32m);
        int c2 = n >> 5, lhi = ((n >> 3) & 3) * 16, j2 = n & 7;
        for (int rg = 0; rg < 4; rg++) {
            float h = fmaxf(acc[j][rg] + bv, 0.0f);
            W_[(c2 * 64 + lhi + lq * 4 + rg) * 8 + j2] = bfbits(h);
        }
    }

    __syncthreads();   // phase-lock waves -> shared Wf2 stream hits L1

    // ---- GEMM2
    for (int j = 0; j < 8; j++)
        for (int r = 0; r < 4; r++) acc[j][r] = 0.0f;
    for (int c = 0; c < 4; c++) {
        bf16x8 a2 = *(const bf16x8*)(W_ + (c * 64 + l) * 8);
        for (int j = 0; j < 8; j++) {
            bf16x8 bf = *(const bf16x8*)(Wf2 + (size_t)(((j * 4 + c) * 64 + l) * 8));
            acc[j] = __builtin_amdgcn_mfma_f32_16x16x32_bf16(a2, bf, acc[j], 0, 0, 0);
        }
    }

    // ---- C2 + b2 -> row-major in wave region
    for (int j = 0; j < 8; j++) {
        int n = j * 16 + ln;
        float bv = xv(bias2, n, f32m);
        for (int rg = 0; rg < 4; rg++)
            W_[(lq * 4 + rg) * 128 + n] = bfbits(acc[j][rg] + bv);
    }

    if (mode == 1) {
        // sequential col0-order copy (A for iteration 2) — nontemporal
        for (int i = 0; i < 4; i++) {
            int idx = i * 64 + l;
            __builtin_nontemporal_store(((const u32x4*)W_)[idx],
                                        (u32x4*)Oc0 + (size_t)e0 * 16 + idx);
        }
    }
    // scatter to col1 positions (full 256B rows) — nontemporal
    for (int i = 0; i < 4; i++) {
        int idx = i * 64 + l;
        int r = idx >> 4;
        int tgt = p0[e0 + r];
        __builtin_nontemporal_store(((const u32x4*)W_)[idx],
                                    (u32x4*)Oc1 + (size_t)tgt * 16 + (idx & 15));
    }
}

// out[n] = x[n] + relu(mean over in-edges of lgX2 rows lo..hi) (0 if deg==0).
__global__ void LGNNGINELayer_12463995093126_kernel(
    const void* x, const unsigned short* lgX, const int* row_ptr,
    void* out, const int* flg) {
    int n = blockIdx.x * 4 + (threadIdx.x >> 6);
    if (n >= NN) return;
    int l = threadIdx.x & 63, k0 = l * 2;
    int f32m = flg[0];
    int lo = row_ptr[n], hi = row_ptr[n + 1];
    float a0_ = 0.0f, a1_ = 0.0f;
    for (int p = lo; p < hi; p++) {
        unsigned u = *(const unsigned*)(lgX + (size_t)p * 128 + k0);
        a0_ += b2f((unsigned short)u);
        a1_ += b2f((unsigned short)(u >> 16));
    }
    float g0 = 0.0f, g1 = 0.0f;
    if (hi > lo) {
        float inv = 1.0f / (float)(hi - lo);
        g0 = fmaxf(a0_ * inv, 0.0f);
        g1 = fmaxf(a1_ * inv, 0.0f);
    }
    if (f32m) {
        ((float*)out)[(long)n * 128 + k0]     = ((const float*)x)[(long)n * 128 + k0] + g0;
        ((float*)out)[(long)n * 128 + k0 + 1] = ((const float*)x)[(long)n * 128 + k0 + 1] + g1;
    } else {
        unsigned u = *(const unsigned*)((const unsigned short*)x + (long)n * 128 + k0);
        float r0 = b2f((unsigned short)u) + g0;
        float r1 = b2f((unsigned short)(u >> 16)) + g1;
        *(unsigned*)((unsigned short*)out + (long)n * 128 + k0) = pkbf(r0, r1);
    }
}

extern "C" void kernel_launch(void* const* d_in, const int* in_sizes, int n_in,
                              void* d_out, int out_size, void* d_ws, size_t ws_size,
                              hipStream_t stream) {
    (void)in_sizes; (void)n_in; (void)out_size; (void)ws_size;
    const void* x = d_in[0];
    const void* W1 = d_in[1];
    const void* b1 = d_in[2];
    const void* W2 = d_in[3];
    const void* b2 = d_in[4];
    const int* col0 = (const int*)d_in[5];
    const int* col1 = (const int*)d_in[6];

    char* p = (char*)d_ws;
    unsigned short* lgXc0 = (unsigned short*)p; p += (size_t)EE * 128 * 2;
    unsigned short* lgXc1 = (unsigned short*)p; p += (size_t)EE * 128 * 2;
    unsigned short* T = (unsigned short*)p;     p += (size_t)NN * 128 * 2;  // T1 then S2
    unsigned short* xb = (unsigned short*)p;    p += (size_t)NN * 128 * 2;
    int* row_ptr = (int*)p;                     p += (size_t)(NN + 16) * 4;
    int* cursor1 = (int*)p;                     p += (size_t)NN * 4;
    int* cursor0 = (int*)p;                     p += (size_t)NN * 4;
    int* counts = (int*)p;                      p += (size_t)2 * NN * 4;
    int* bsum = (int*)p;                        p += 512 * 4;
    unsigned* aux = (unsigned*)p;               p += (size_t)EE * 4;
    int* a0 = (int*)p;                          p += (size_t)EE * 4;
    int* b0 = (int*)p;                          p += (size_t)EE * 4;
    int* p0 = (int*)p;                          p += (size_t)EE * 4;
    int* flg = (int*)p;                         p += 256;
    unsigned short* Wf1 = (unsigned short*)p;   p += 16384 * 2;
    unsigned short* Wf2 = (unsigned short*)p;

    int gB = EE / 64;                  // 3125 fused blocks
    int eB = (EE + 255) / 256;
    int nB4 = (NN + 3) / 4;

    k_detect<<<1, 1024, 0, stream>>>((const unsigned short*)x, col0, flg);
    k_prep<<<CB + 16, 256, 0, stream>>>(x, xb, W1, W2, Wf1, Wf2, flg);

    // both CSRs in one chain
    (void)hipMemsetAsync(counts, 0, (size_t)2 * NN * 4, stream);
    k_hist2<<<eB, 256, 0, stream>>>(col0, col1, counts, flg);
    k_scan1<<<2 * SB, 256, 0, stream>>>(counts, bsum);
    k_scan2<<<2 * SB, 256, 0, stream>>>(counts, bsum, row_ptr, cursor1, cursor0);
    k_cscatter2<<<eB, 256, 0, stream>>>(col0, col1, cursor1, cursor0,
                                        aux, a0, b0, p0, flg);

    // iteration 1: T1 = S1 + 0.5*xb; fused MLP (col0-order) -> lgX in both orders
    k_gath<<<nB4, 256, 0, stream>>>(xb, lgXc1, row_ptr, aux, T, 1);
    k_fused<<<gB, 256, 0, stream>>>(T, lgXc0, xb, a0, b0, p0, b1, b2,
                                    Wf1, Wf2, lgXc0, lgXc1, flg, 1);
    // iteration 2: S2 from lgXc1 (sequential); fused MLP (all-seq reads) -> lgXc1
    k_gath<<<nB4, 256, 0, stream>>>(xb, lgXc1, row_ptr, aux, T, 2);
    k_fused<<<gB, 256, 0, stream>>>(T, lgXc0, xb, a0, b0, p0, b1, b2,
                                    Wf1, Wf2, lgXc0, lgXc1, flg, 2);
    // mean + residual (sequential CSR read)
    LGNNGINELayer_12463995093126_kernel<<<nB4, 256, 0, stream>>>(
        x, lgXc1, row_ptr, d_out, flg);
}

// Round 15
// 379.108 us; speedup vs baseline: 1.1018x; 1.1018x over previous
//
#include <hip/hip_runtime.h>
#include <hip/hip_bf16.h>

constexpr int NN = 50000;
constexpr int EE = 200000;
typedef __bf16 bf16x8 __attribute__((ext_vector_type(8)));
typedef float f32x4 __attribute__((ext_vector_type(4)));

__device__ __forceinline__ float b2f(unsigned short s) {
    union { unsigned u; float f; } c; c.u = ((unsigned)s) << 16; return c.f;
}
// native RTNE f32->bf16 (compiler emits v_cvt_pk_bf16_f32 for pairs)
__device__ __forceinline__ unsigned short bfbits(float f) {
    union { __bf16 b; unsigned short u; } c; c.b = (__bf16)f; return c.u;
}
__device__ __forceinline__ unsigned pkbf(float lo, float hi) {
    return ((unsigned)bfbits(hi) << 16) | bfbits(lo);
}
__device__ __forceinline__ float xv(const void* p, long i, int f32m) {
    return f32m ? ((const float*)p)[i] : b2f(((const unsigned short*)p)[i]);
}
__device__ __forceinline__ int iv(const int* p, int i, int i64m) {
    return i64m ? p[2 * i] : p[i];
}

// parallel dtype sniff
__global__ void k_detect(const unsigned short* x16, const int* c32, int* flg) {
    __shared__ int sf, si;
    int t = threadIdx.x;
    if (t == 0) { sf = 0; si = 1; }
    __syncthreads();
    for (int i = t; i < 16384; i += 1024)
        if (((x16[i] >> 7) & 0xFF) == 0xFF) sf = 1;
    if (t < 64)
        if (c32[2 * t + 1] != 0) si = 0;
    __syncthreads();
    if (t == 0) { flg[0] = sf; flg[1] = si; }
}

// x -> bf16 image xb (all structural gathers read this; half the bytes of f32)
__global__ void k_cast(const void* x, unsigned short* xb, const int* flg) {
    int i = blockIdx.x * 256 + threadIdx.x;       // 8 elements per thread
    if (i >= NN * 16) return;
    if (flg[0]) {
        const float4* xp = (const float4*)x + (size_t)i * 2;
        float4 u = xp[0], v = xp[1];
        uint4 o;
        o.x = pkbf(u.x, u.y); o.y = pkbf(u.z, u.w);
        o.z = pkbf(v.x, v.y); o.w = pkbf(v.z, v.w);
        ((uint4*)xb)[i] = o;
    } else {
        ((uint4*)xb)[i] = ((const uint4*)x)[i];
    }
}

// Pack W1,W2 into bf16 MFMA B-fragment images in ONE dispatch (grid 16).
// chunk=(t*4+c)*64+l ; Wf[chunk*8+j] = W[c*32+(l>>4)*8+j][t*16+(l&15)]
__global__ void k_wfrag2(const void* W1, const void* W2,
                         unsigned short* Wf1, unsigned short* Wf2, const int* flg) {
    int f32m = flg[0];
    int g = blockIdx.x;
    const void* W = (g < 8) ? W1 : W2;
    unsigned short* Wf = (g < 8) ? Wf1 : Wf2;
    int chunk = (g & 7) * 256 + threadIdx.x;
    int l = chunk & 63, c = (chunk >> 6) & 3, t = chunk >> 8;
    int n = t * 16 + (l & 15), k0 = c * 32 + ((l >> 4) * 8);
    for (int j = 0; j < 8; j++) Wf[chunk * 8 + j] = bfbits(xv(W, (long)(k0 + j) * 128 + n, f32m));
}

// ---- CSR build (by col1), done once ----
__global__ void k_hist(const int* col1, int* counts, const int* flg) {
    int e = blockIdx.x * 256 + threadIdx.x;
    if (e >= EE) return;
    atomicAdd(&counts[iv(col1, e, flg[1])], 1);
}

// multi-block scan, stage 1: per-block sums (256 counts/block)
__global__ void k_scan1(const int* counts, int* bsum) {
    __shared__ int sh[256];
    int b = blockIdx.x, t = threadIdx.x;
    int idx = b * 256 + t;
    sh[t] = (idx < NN) ? counts[idx] : 0;
    __syncthreads();
    for (int off = 128; off > 0; off >>= 1) {
        if (t < off) sh[t] += sh[t + off];
        __syncthreads();
    }
    if (t == 0) bsum[b] = sh[0];
}

// stage 2: base = sum(bsum[0..b)), intra-block exclusive scan -> row_ptr/cursor
__global__ void k_scan2(const int* counts, const int* bsum,
                        int* row_ptr, int* cursor) {
    __shared__ int sh[256];
    __shared__ int base_s;
    int b = blockIdx.x, t = threadIdx.x;
    sh[t] = (t < b) ? bsum[t] : 0;
    __syncthreads();
    for (int off = 128; off > 0; off >>= 1) {
        if (t < off) sh[t] += sh[t + off];
        __syncthreads();
    }
    if (t == 0) base_s = sh[0];
    __syncthreads();
    int idx = b * 256 + t;
    int v = (idx < NN) ? counts[idx] : 0;
    sh[t] = v;
    __syncthreads();
    for (int off = 1; off < 256; off <<= 1) {
        int add = (t >= off) ? sh[t - off] : 0;
        __syncthreads();
        sh[t] += add;
        __syncthreads();
    }
    int ex = base_s + sh[t] - v;   // exclusive prefix
    if (idx < NN) { row_ptr[idx] = ex; cursor[idx] = ex; }
    if (idx == NN - 1) row_ptr[NN] = ex + v;
}

// position p (CSR slot under col1): aux[p] = col0[e] | selfloop<<31; node1[p] = col1[e].
// lgX is stored PERMUTED: edge e's features live at row p.
__global__ void k_cscatter(const int* col0, const int* col1, int* cursor,
                           unsigned* aux, int* node1, const int* flg) {
    int e = blockIdx.x * 256 + threadIdx.x;
    if (e >= EE) return;
    int i64m = flg[1];
    int a = iv(col0, e, i64m), b = iv(col1, e, i64m);
    int pos = atomicAdd(&cursor[b], 1);
    aux[pos] = (unsigned)a | (a == b ? 0x80000000u : 0u);
    node1[pos] = b;
}

// S[n][k] (bf16) = sum over non-self-loop in-edges of relu(msg).
//   mode 1: msg = 0.5*xb[col0] + 1.5*xb[n]   (bf16 gather, 256B rows)
//   mode 2: msg = lgX[p] + xb[n]             (SEQUENTIAL rows lo..hi)
// One wave per node; lane owns columns 2l,2l+1.
__global__ void k_gath(const unsigned short* xb, const unsigned short* lgX,
                       const int* row_ptr, const unsigned* aux,
                       unsigned short* S, int mode) {
    int n = blockIdx.x * 4 + (threadIdx.x >> 6);
    if (n >= NN) return;
    int l = threadIdx.x & 63, k0 = l * 2;
    int lo = row_ptr[n], hi = row_ptr[n + 1];
    unsigned un = *(const unsigned*)(xb + (size_t)n * 128 + k0);
    float xn0 = b2f((unsigned short)un), xn1 = b2f((unsigned short)(un >> 16));
    float a0 = 0.0f, a1 = 0.0f;
    if (mode == 1) {
        for (int p = lo; p < hi; p++) {
            unsigned av = aux[p];
            if (av & 0x80000000u) continue;
            unsigned u = *(const unsigned*)(xb + (size_t)av * 128 + k0);
            a0 += fmaxf(0.5f * b2f((unsigned short)u) + 1.5f * xn0, 0.0f);
            a1 += fmaxf(0.5f * b2f((unsigned short)(u >> 16)) + 1.5f * xn1, 0.0f);
        }
    } else {
        for (int p = lo; p < hi; p++) {
            if (aux[p] & 0x80000000u) continue;
            unsigned u = *(const unsigned*)(lgX + (size_t)p * 128 + k0);   // sequential
            a0 += fmaxf(b2f((unsigned short)u) + xn0, 0.0f);
            a1 += fmaxf(b2f((unsigned short)(u >> 16)) + xn1, 0.0f);
        }
    }
    *(unsigned*)(S + (size_t)n * 128 + k0) = pkbf(a0, a1);
}

// Fused 2-layer MLP, BARRIER-FREE: each wave owns 16 CSR positions end-to-end.
// Out = (relu((A + S[col0]) @ W1 + b1)) @ W2 + b2, in-place on permuted lgX.
// A-frags live in registers; LDS only for the genuinely cross-lane
// H-transpose and C2 store-coalescing (wave-private region, lgkmcnt only).
__global__ __launch_bounds__(256, 8)
void k_fused(const unsigned short* A, const unsigned short* S,
             const unsigned* aux, const int* node1, const unsigned short* xb,
             const void* bias1, const void* bias2,
             const unsigned short* Wf1, const unsigned short* Wf2,
             unsigned short* Out, const int* flg, int initA) {
    __shared__ unsigned short Lds[8192];   // 16 KB: 4 waves x 4 KB
    int f32m = flg[0];
    int tid = threadIdx.x;
    int w = tid >> 6, l = tid & 63;
    int lq = l >> 4, ln = l & 15;
    int e0 = blockIdx.x * 64 + w * 16;     // wave's 16 positions (EE % 64 == 0)
    unsigned short* W_ = Lds + w * 2048;   // wave-private region

    // ---- stage A-frag IN REGISTERS: lane l = row e0+ln, k-group lq*8, c=0..3
    int row = e0 + ln;
    int aN = (int)(aux[row] & 0x7fffffffu);
    int bN = initA ? node1[row] : 0;
    bf16x8 af[4];
    for (int c = 0; c < 4; c++) {
        int k0 = c * 32 + lq * 8;
        uint4 svv = *(const uint4*)(S + (size_t)aN * 128 + k0);
        const unsigned short* sp = (const unsigned short*)&svv;
        if (initA) {
            uint4 xav = *(const uint4*)(xb + (size_t)aN * 128 + k0);
            uint4 xbv = *(const uint4*)(xb + (size_t)bN * 128 + k0);
            const unsigned short* xa = (const unsigned short*)&xav;
            const unsigned short* xc = (const unsigned short*)&xbv;
            for (int j = 0; j < 8; j++)
                af[c][j] = (__bf16)(0.5f * (b2f(xa[j]) + b2f(xc[j])) + b2f(sp[j]));
        } else {
            uint4 av = *(const uint4*)(A + (size_t)row * 128 + k0);
            const unsigned short* ap = (const unsigned short*)&av;
            for (int j = 0; j < 8; j++)
                af[c][j] = (__bf16)(b2f(ap[j]) + b2f(sp[j]));
        }
    }

    // ---- GEMM1: rows 16, cols 128
    f32x4 acc[8];
    for (int j = 0; j < 8; j++)
        for (int r = 0; r < 4; r++) acc[j][r] = 0.0f;
    for (int c = 0; c < 4; c++) {
        for (int j = 0; j < 8; j++) {
            bf16x8 bf = *(const bf16x8*)(Wf1 + (size_t)(((j * 4 + c) * 64 + l) * 8));
            acc[j] = __builtin_amdgcn_mfma_f32_16x16x32_bf16(af[c], bf, acc[j], 0, 0, 0);
        }
    }

    // ---- H = relu(C1+b1) -> LDS in A-frag order (cross-lane transpose)
    for (int j = 0; j < 8; j++) {
        int n = j * 16 + ln;
        float bv = xv(bias1, n, f32m);
        int c2 = n >> 5, lhi = ((n >> 3) & 3) * 16, j2 = n & 7;
        for (int rg = 0; rg < 4; rg++) {
            float h = fmaxf(acc[j][rg] + bv, 0.0f);
            W_[(c2 * 64 + lhi + lq * 4 + rg) * 8 + j2] = bfbits(h);
        }
    }

    // ---- GEMM2 (A-frag for H read from LDS; DS ops are in-order per wave)
    for (int j = 0; j < 8; j++)
        for (int r = 0; r < 4; r++) acc[j][r] = 0.0f;
    for (int c = 0; c < 4; c++) {
        bf16x8 a2 = *(const bf16x8*)(W_ + (c * 64 + l) * 8);
        for (int j = 0; j < 8; j++) {
            bf16x8 bf = *(const bf16x8*)(Wf2 + (size_t)(((j * 4 + c) * 64 + l) * 8));
            acc[j] = __builtin_amdgcn_mfma_f32_16x16x32_bf16(a2, bf, acc[j], 0, 0, 0);
        }
    }

    // ---- C2 + b2 -> row-major in region, then coalesced uint4 store
    for (int j = 0; j < 8; j++) {
        int n = j * 16 + ln;
        float bv = xv(bias2, n, f32m);
        for (int rg = 0; rg < 4; rg++)
            W_[(lq * 4 + rg) * 128 + n] = bfbits(acc[j][rg] + bv);
    }
    for (int i = 0; i < 4; i++) {
        int idx = i * 64 + l;    // 256 uint4 = 16 rows x 256B
        ((uint4*)Out)[(size_t)e0 * 16 + idx] = ((const uint4*)W_)[idx];
    }
}

// out[n] = x[n] + relu(mean over ALL in-edges of lgX rows lo..hi) (0 if deg==0).
// Fully sequential reads; residual uses original-precision x.
__global__ void LGNNGINELayer_12463995093126_kernel(
    const void* x, const unsigned short* lgX, const int* row_ptr,
    void* out, const int* flg) {
    int n = blockIdx.x * 4 + (threadIdx.x >> 6);
    if (n >= NN) return;
    int l = threadIdx.x & 63, k0 = l * 2;
    int f32m = flg[0];
    int lo = row_ptr[n], hi = row_ptr[n + 1];
    float a0 = 0.0f, a1 = 0.0f;
    for (int p = lo; p < hi; p++) {
        unsigned u = *(const unsigned*)(lgX + (size_t)p * 128 + k0);
        a0 += b2f((unsigned short)u);
        a1 += b2f((unsigned short)(u >> 16));
    }
    float g0 = 0.0f, g1 = 0.0f;
    if (hi > lo) {
        float inv = 1.0f / (float)(hi - lo);
        g0 = fmaxf(a0 * inv, 0.0f);
        g1 = fmaxf(a1 * inv, 0.0f);
    }
    if (f32m) {
        ((float*)out)[(long)n * 128 + k0]     = ((const float*)x)[(long)n * 128 + k0] + g0;
        ((float*)out)[(long)n * 128 + k0 + 1] = ((const float*)x)[(long)n * 128 + k0 + 1] + g1;
    } else {
        unsigned u = *(const unsigned*)((const unsigned short*)x + (long)n * 128 + k0);
        float r0 = b2f((unsigned short)u) + g0;
        float r1 = b2f((unsigned short)(u >> 16)) + g1;
        *(unsigned*)((unsigned short*)out + (long)n * 128 + k0) = pkbf(r0, r1);
    }
}

extern "C" void kernel_launch(void* const* d_in, const int* in_sizes, int n_in,
                              void* d_out, int out_size, void* d_ws, size_t ws_size,
                              hipStream_t stream) {
    (void)in_sizes; (void)n_in; (void)out_size; (void)ws_size;
    const void* x = d_in[0];
    const void* W1 = d_in[1];
    const void* b1 = d_in[2];
    const void* W2 = d_in[3];
    const void* b2 = d_in[4];
    const int* col0 = (const int*)d_in[5];
    const int* col1 = (const int*)d_in[6];

    // ws: lgX(csr) | S | xb | row_ptr | cursor | counts | bsum | aux | node1 | flg | Wf1 | Wf2
    char* p = (char*)d_ws;
    unsigned short* lgX = (unsigned short*)p; p += (size_t)EE * 128 * 2;
    unsigned short* S = (unsigned short*)p;   p += (size_t)NN * 128 * 2;
    unsigned short* xb = (unsigned short*)p;  p += (size_t)NN * 128 * 2;
    int* row_ptr = (int*)p;                   p += (size_t)(NN + 16) * 4;
    int* cursor = (int*)p;                    p += (size_t)NN * 4;
    int* counts = (int*)p;                    p += (size_t)NN * 4;
    int* bsum = (int*)p;                      p += 256 * 4;
    unsigned* aux = (unsigned*)p;             p += (size_t)EE * 4;
    int* node1 = (int*)p;                     p += (size_t)EE * 4;
    int* flg = (int*)p;                       p += 256;
    unsigned short* Wf1 = (unsigned short*)p; p += 16384 * 2;
    unsigned short* Wf2 = (unsigned short*)p;

    int gB = EE / 64;                  // 3125 blocks, wave = 16 positions
    int eB = (EE + 255) / 256;
    int nB4 = (NN + 3) / 4;
    int sB = (NN + 255) / 256;         // 196 scan blocks
    int cB = (NN * 16 + 255) / 256;    // cast blocks

    k_detect<<<1, 1024, 0, stream>>>((const unsigned short*)x, col0, flg);
    k_cast<<<cB, 256, 0, stream>>>(x, xb, flg);
    k_wfrag2<<<16, 256, 0, stream>>>(W1, W2, Wf1, Wf2, flg);

    // CSR by col1 (col1 fixed across iterations)
    (void)hipMemsetAsync(counts, 0, (size_t)NN * 4, stream);
    k_hist<<<eB, 256, 0, stream>>>(col1, counts, flg);
    k_scan1<<<sB, 256, 0, stream>>>(counts, bsum);
    k_scan2<<<sB, 256, 0, stream>>>(counts, bsum, row_ptr, cursor);
    k_cscatter<<<eB, 256, 0, stream>>>(col0, col1, cursor, aux, node1, flg);

    // iteration 1: S from xb directly, fused MLP -> lgX (CSR-permuted)
    k_gath<<<nB4, 256, 0, stream>>>(xb, lgX, row_ptr, aux, S, 1);
    k_fused<<<gB, 256, 0, stream>>>(lgX, S, aux, node1, xb, b1, b2,
                                    Wf1, Wf2, lgX, flg, 1);
    // iteration 2 (lgX reads sequential in k_gath)
    k_gath<<<nB4, 256, 0, stream>>>(xb, lgX, row_ptr, aux, S, 2);
    k_fused<<<gB, 256, 0, stream>>>(lgX, S, aux, node1, xb, b1, b2,
                                    Wf1, Wf2, lgX, flg, 0);
    // scatter_mean back to nodes (sequential CSR read) + residual/relu
    LGNNGINELayer_12463995093126_kernel<<<nB4, 256, 0, stream>>>(
        x, lgX, row_ptr, d_out, flg);
}

// Round 17
// 346.402 us; speedup vs baseline: 1.2058x; 1.0944x over previous
//
#include <hip/hip_runtime.h>
#include <hip/hip_bf16.h>

constexpr int NN = 50000;
constexpr int EE = 200000;
typedef __bf16 bf16x8 __attribute__((ext_vector_type(8)));
typedef float f32x4 __attribute__((ext_vector_type(4)));

__device__ __forceinline__ float b2f(unsigned short s) {
    union { unsigned u; float f; } c; c.u = ((unsigned)s) << 16; return c.f;
}
// native RTNE f32->bf16 (compiler emits v_cvt_pk_bf16_f32 for pairs)
__device__ __forceinline__ unsigned short bfbits(float f) {
    union { __bf16 b; unsigned short u; } c; c.b = (__bf16)f; return c.u;
}
__device__ __forceinline__ unsigned pkbf(float lo, float hi) {
    return ((unsigned)bfbits(hi) << 16) | bfbits(lo);
}
__device__ __forceinline__ float xv(const void* p, long i, int f32m) {
    return f32m ? ((const float*)p)[i] : b2f(((const unsigned short*)p)[i]);
}
__device__ __forceinline__ int iv(const int* p, int i, int i64m) {
    return i64m ? p[2 * i] : p[i];
}

// parallel dtype sniff
__global__ void k_detect(const unsigned short* x16, const int* c32, int* flg) {
    __shared__ int sf, si;
    int t = threadIdx.x;
    if (t == 0) { sf = 0; si = 1; }
    __syncthreads();
    for (int i = t; i < 16384; i += 1024)
        if (((x16[i] >> 7) & 0xFF) == 0xFF) sf = 1;
    if (t < 64)
        if (c32[2 * t + 1] != 0) si = 0;
    __syncthreads();
    if (t == 0) { flg[0] = sf; flg[1] = si; }
}

// x -> bf16 image xb (all structural gathers read this; half the bytes of f32)
__global__ void k_cast(const void* x, unsigned short* xb, const int* flg) {
    int i = blockIdx.x * 256 + threadIdx.x;       // 8 elements per thread
    if (i >= NN * 16) return;
    if (flg[0]) {
        const float4* xp = (const float4*)x + (size_t)i * 2;
        float4 u = xp[0], v = xp[1];
        uint4 o;
        o.x = pkbf(u.x, u.y); o.y = pkbf(u.z, u.w);
        o.z = pkbf(v.x, v.y); o.w = pkbf(v.z, v.w);
        ((uint4*)xb)[i] = o;
    } else {
        ((uint4*)xb)[i] = ((const uint4*)x)[i];
    }
}

// Pack W1,W2 into bf16 MFMA B-fragment images in ONE dispatch (grid 16).
// chunk=(t*4+c)*64+l ; Wf[chunk*8+j] = W[c*32+(l>>4)*8+j][t*16+(l&15)]
__global__ void k_wfrag2(const void* W1, const void* W2,
                         unsigned short* Wf1, unsigned short* Wf2, const int* flg) {
    int f32m = flg[0];
    int g = blockIdx.x;
    const void* W = (g < 8) ? W1 : W2;
    unsigned short* Wf = (g < 8) ? Wf1 : Wf2;
    int chunk = (g & 7) * 256 + threadIdx.x;
    int l = chunk & 63, c = (chunk >> 6) & 3, t = chunk >> 8;
    int n = t * 16 + (l & 15), k0 = c * 32 + ((l >> 4) * 8);
    for (int j = 0; j < 8; j++) Wf[chunk * 8 + j] = bfbits(xv(W, (long)(k0 + j) * 128 + n, f32m));
}

// ---- CSR build (by col1), done once ----
__global__ void k_hist(const int* col1, int* counts, const int* flg) {
    int e = blockIdx.x * 256 + threadIdx.x;
    if (e >= EE) return;
    atomicAdd(&counts[iv(col1, e, flg[1])], 1);
}

// multi-block scan, stage 1: per-block sums (256 counts/block)
__global__ void k_scan1(const int* counts, int* bsum) {
    __shared__ int sh[256];
    int b = blockIdx.x, t = threadIdx.x;
    int idx = b * 256 + t;
    sh[t] = (idx < NN) ? counts[idx] : 0;
    __syncthreads();
    for (int off = 128; off > 0; off >>= 1) {
        if (t < off) sh[t] += sh[t + off];
        __syncthreads();
    }
    if (t == 0) bsum[b] = sh[0];
}

// stage 2: base = sum(bsum[0..b)), intra-block exclusive scan -> row_ptr/cursor
__global__ void k_scan2(const int* counts, const int* bsum,
                        int* row_ptr, int* cursor) {
    __shared__ int sh[256];
    __shared__ int base_s;
    int b = blockIdx.x, t = threadIdx.x;
    sh[t] = (t < b) ? bsum[t] : 0;
    __syncthreads();
    for (int off = 128; off > 0; off >>= 1) {
        if (t < off) sh[t] += sh[t + off];
        __syncthreads();
    }
    if (t == 0) base_s = sh[0];
    __syncthreads();
    int idx = b * 256 + t;
    int v = (idx < NN) ? counts[idx] : 0;
    sh[t] = v;
    __syncthreads();
    for (int off = 1; off < 256; off <<= 1) {
        int add = (t >= off) ? sh[t - off] : 0;
        __syncthreads();
        sh[t] += add;
        __syncthreads();
    }
    int ex = base_s + sh[t] - v;   // exclusive prefix
    if (idx < NN) { row_ptr[idx] = ex; cursor[idx] = ex; }
    if (idx == NN - 1) row_ptr[NN] = ex + v;
}

// position p (CSR slot under col1): aux[p] = col0[e] | selfloop<<31; node1[p] = col1[e].
// lgX is stored PERMUTED: edge e's features live at row p.
__global__ void k_cscatter(const int* col0, const int* col1, int* cursor,
                           unsigned* aux, int* node1, const int* flg) {
    int e = blockIdx.x * 256 + threadIdx.x;
    if (e >= EE) return;
    int i64m = flg[1];
    int a = iv(col0, e, i64m), b = iv(col1, e, i64m);
    int pos = atomicAdd(&cursor[b], 1);
    aux[pos] = (unsigned)a | (a == b ? 0x80000000u : 0u);
    node1[pos] = b;
}

// S[n][k] (bf16) = sum over non-self-loop in-edges of relu(msg).
//   mode 1: msg = 0.5*xb[col0] + 1.5*xb[n]   (bf16 gather, 256B rows)
//   mode 2: msg = lgX[p] + xb[n]             (SEQUENTIAL rows lo..hi)
// One wave per node; lane owns columns 2l,2l+1.
__global__ void k_gath(const unsigned short* xb, const unsigned short* lgX,
                       const int* row_ptr, const unsigned* aux,
                       unsigned short* S, int mode) {
    int n = blockIdx.x * 4 + (threadIdx.x >> 6);
    if (n >= NN) return;
    int l = threadIdx.x & 63, k0 = l * 2;
    int lo = row_ptr[n], hi = row_ptr[n + 1];
    unsigned un = *(const unsigned*)(xb + (size_t)n * 128 + k0);
    float xn0 = b2f((unsigned short)un), xn1 = b2f((unsigned short)(un >> 16));
    float a0 = 0.0f, a1 = 0.0f;
    if (mode == 1) {
        for (int p = lo; p < hi; p++) {
            unsigned av = aux[p];
            if (av & 0x80000000u) continue;
            unsigned u = *(const unsigned*)(xb + (size_t)av * 128 + k0);
            a0 += fmaxf(0.5f * b2f((unsigned short)u) + 1.5f * xn0, 0.0f);
            a1 += fmaxf(0.5f * b2f((unsigned short)(u >> 16)) + 1.5f * xn1, 0.0f);
        }
    } else {
        for (int p = lo; p < hi; p++) {
            if (aux[p] & 0x80000000u) continue;
            unsigned u = *(const unsigned*)(lgX + (size_t)p * 128 + k0);   // sequential
            a0 += fmaxf(b2f((unsigned short)u) + xn0, 0.0f);
            a1 += fmaxf(b2f((unsigned short)(u >> 16)) + xn1, 0.0f);
        }
    }
    *(unsigned*)(S + (size_t)n * 128 + k0) = pkbf(a0, a1);
}

// Fused 2-layer MLP, BARRIER-FREE: each wave owns 32 CSR positions (2 row-tiles).
// KEY: each Wf B-fragment is loaded ONCE and feeds TWO MFMAs (one per row-tile),
// halving the per-row Wf read traffic (the L2-bandwidth floor identified r15).
// A-frags in registers; wave-private 8KB LDS for H-transpose + C2 coalescing.
__global__ __launch_bounds__(256, 4)
void k_fused(const unsigned short* A, const unsigned short* S,
             const unsigned* aux, const int* node1, const unsigned short* xb,
             const void* bias1, const void* bias2,
             const unsigned short* Wf1, const unsigned short* Wf2,
             unsigned short* Out, const int* flg, int initA) {
    __shared__ unsigned short Lds[16384];  // 32 KB: 4 waves x 8 KB
    int f32m = flg[0];
    int tid = threadIdx.x;
    int w = tid >> 6, l = tid & 63;
    int lq = l >> 4, ln = l & 15;
    int e0 = blockIdx.x * 128 + w * 32;    // wave's 32 positions
    if (e0 >= EE) return;                  // tail is whole-wave (EE % 32 == 0)
    unsigned short* W_ = Lds + w * 4096;   // wave-private 8 KB region

    // ---- stage A-frags IN REGISTERS for both row-tiles
    bf16x8 af[2][4];
    for (int t = 0; t < 2; t++) {
        int row = e0 + t * 16 + ln;
        int aN = (int)(aux[row] & 0x7fffffffu);
        int bN = initA ? node1[row] : 0;
        for (int c = 0; c < 4; c++) {
            int k0 = c * 32 + lq * 8;
            uint4 svv = *(const uint4*)(S + (size_t)aN * 128 + k0);
            const unsigned short* sp = (const unsigned short*)&svv;
            if (initA) {
                uint4 xav = *(const uint4*)(xb + (size_t)aN * 128 + k0);
                uint4 xbv = *(const uint4*)(xb + (size_t)bN * 128 + k0);
                const unsigned short* xa = (const unsigned short*)&xav;
                const unsigned short* xc = (const unsigned short*)&xbv;
                for (int j = 0; j < 8; j++)
                    af[t][c][j] = (__bf16)(0.5f * (b2f(xa[j]) + b2f(xc[j])) + b2f(sp[j]));
            } else {
                uint4 av = *(const uint4*)(A + (size_t)row * 128 + k0);
                const unsigned short* ap = (const unsigned short*)&av;
                for (int j = 0; j < 8; j++)
                    af[t][c][j] = (__bf16)(b2f(ap[j]) + b2f(sp[j]));
            }
        }
    }

    // ---- GEMM1: 32 rows x 128 cols; each bf load feeds 2 MFMAs
    f32x4 acc[2][8];
    for (int t = 0; t < 2; t++)
        for (int j = 0; j < 8; j++)
            for (int r = 0; r < 4; r++) acc[t][j][r] = 0.0f;
    for (int c = 0; c < 4; c++) {
        for (int j = 0; j < 8; j++) {
            bf16x8 bf = *(const bf16x8*)(Wf1 + (size_t)(((j * 4 + c) * 64 + l) * 8));
            acc[0][j] = __builtin_amdgcn_mfma_f32_16x16x32_bf16(af[0][c], bf, acc[0][j], 0, 0, 0);
            acc[1][j] = __builtin_amdgcn_mfma_f32_16x16x32_bf16(af[1][c], bf, acc[1][j], 0, 0, 0);
        }
    }

    // ---- H = relu(C1+b1) -> LDS in A-frag order, per tile (cross-lane transpose)
    for (int t = 0; t < 2; t++) {
        for (int j = 0; j < 8; j++) {
            int n = j * 16 + ln;
            float bv = xv(bias1, n, f32m);
            int c2 = n >> 5, lhi = ((n >> 3) & 3) * 16, j2 = n & 7;
            for (int rg = 0; rg < 4; rg++) {
                float h = fmaxf(acc[t][j][rg] + bv, 0.0f);
                W_[t * 2048 + (c2 * 64 + lhi + lq * 4 + rg) * 8 + j2] = bfbits(h);
            }
        }
    }

    // ---- GEMM2: each bf load feeds 2 MFMAs (A from LDS, per-wave in-order)
    for (int t = 0; t < 2; t++)
        for (int j = 0; j < 8; j++)
            for (int r = 0; r < 4; r++) acc[t][j][r] = 0.0f;
    for (int c = 0; c < 4; c++) {
        bf16x8 a20 = *(const bf16x8*)(W_ + (c * 64 + l) * 8);
        bf16x8 a21 = *(const bf16x8*)(W_ + 2048 + (c * 64 + l) * 8);
        for (int j = 0; j < 8; j++) {
            bf16x8 bf = *(const bf16x8*)(Wf2 + (size_t)(((j * 4 + c) * 64 + l) * 8));
            acc[0][j] = __builtin_amdgcn_mfma_f32_16x16x32_bf16(a20, bf, acc[0][j], 0, 0, 0);
            acc[1][j] = __builtin_amdgcn_mfma_f32_16x16x32_bf16(a21, bf, acc[1][j], 0, 0, 0);
        }
    }

    // ---- C2 + b2 -> row-major in region (tile t at offset t*2048), then store
    for (int t = 0; t < 2; t++) {
        for (int j = 0; j < 8; j++) {
            int n = j * 16 + ln;
            float bv = xv(bias2, n, f32m);
            for (int rg = 0; rg < 4; rg++)
                W_[t * 2048 + (lq * 4 + rg) * 128 + n] = bfbits(acc[t][j][rg] + bv);
        }
    }
    for (int i = 0; i < 8; i++) {
        int idx = i * 64 + l;    // 512 uint4 = 32 rows x 256B
        ((uint4*)Out)[(size_t)e0 * 16 + idx] = ((const uint4*)W_)[idx];
    }
}

// out[n] = x[n] + relu(mean over ALL in-edges of lgX rows lo..hi) (0 if deg==0).
// Fully sequential reads; residual uses original-precision x.
__global__ void LGNNGINELayer_12463995093126_kernel(
    const void* x, const unsigned short* lgX, const int* row_ptr,
    void* out, const int* flg) {
    int n = blockIdx.x * 4 + (threadIdx.x >> 6);
    if (n >= NN) return;
    int l = threadIdx.x & 63, k0 = l * 2;
    int f32m = flg[0];
    int lo = row_ptr[n], hi = row_ptr[n + 1];
    float a0 = 0.0f, a1 = 0.0f;
    for (int p = lo; p < hi; p++) {
        unsigned u = *(const unsigned*)(lgX + (size_t)p * 128 + k0);
        a0 += b2f((unsigned short)u);
        a1 += b2f((unsigned short)(u >> 16));
    }
    float g0 = 0.0f, g1 = 0.0f;
    if (hi > lo) {
        float inv = 1.0f / (float)(hi - lo);
        g0 = fmaxf(a0 * inv, 0.0f);
        g1 = fmaxf(a1 * inv, 0.0f);
    }
    if (f32m) {
        ((float*)out)[(long)n * 128 + k0]     = ((const float*)x)[(long)n * 128 + k0] + g0;
        ((float*)out)[(long)n * 128 + k0 + 1] = ((const float*)x)[(long)n * 128 + k0 + 1] + g1;
    } else {
        unsigned u = *(const unsigned*)((const unsigned short*)x + (long)n * 128 + k0);
        float r0 = b2f((unsigned short)u) + g0;
        float r1 = b2f((unsigned short)(u >> 16)) + g1;
        *(unsigned*)((unsigned short*)out + (long)n * 128 + k0) = pkbf(r0, r1);
    }
}

extern "C" void kernel_launch(void* const* d_in, const int* in_sizes, int n_in,
                              void* d_out, int out_size, void* d_ws, size_t ws_size,
                              hipStream_t stream) {
    (void)in_sizes; (void)n_in; (void)out_size; (void)ws_size;
    const void* x = d_in[0];
    const void* W1 = d_in[1];
    const void* b1 = d_in[2];
    const void* W2 = d_in[3];
    const void* b2 = d_in[4];
    const int* col0 = (const int*)d_in[5];
    const int* col1 = (const int*)d_in[6];

    // ws: lgX(csr) | S | xb | row_ptr | cursor | counts | bsum | aux | node1 | flg | Wf1 | Wf2
    char* p = (char*)d_ws;
    unsigned short* lgX = (unsigned short*)p; p += (size_t)EE * 128 * 2;
    unsigned short* S = (unsigned short*)p;   p += (size_t)NN * 128 * 2;
    unsigned short* xb = (unsigned short*)p;  p += (size_t)NN * 128 * 2;
    int* row_ptr = (int*)p;                   p += (size_t)(NN + 16) * 4;
    int* cursor = (int*)p;                    p += (size_t)NN * 4;
    int* counts = (int*)p;                    p += (size_t)NN * 4;
    int* bsum = (int*)p;                      p += 256 * 4;
    unsigned* aux = (unsigned*)p;             p += (size_t)EE * 4;
    int* node1 = (int*)p;                     p += (size_t)EE * 4;
    int* flg = (int*)p;                       p += 256;
    unsigned short* Wf1 = (unsigned short*)p; p += 16384 * 2;
    unsigned short* Wf2 = (unsigned short*)p;

    int gB = (EE + 127) / 128;         // 1563 blocks, wave = 32 positions
    int eB = (EE + 255) / 256;
    int nB4 = (NN + 3) / 4;
    int sB = (NN + 255) / 256;         // 196 scan blocks
    int cB = (NN * 16 + 255) / 256;    // cast blocks

    k_detect<<<1, 1024, 0, stream>>>((const unsigned short*)x, col0, flg);
    k_cast<<<cB, 256, 0, stream>>>(x, xb, flg);
    k_wfrag2<<<16, 256, 0, stream>>>(W1, W2, Wf1, Wf2, flg);

    // CSR by col1 (col1 fixed across iterations)
    (void)hipMemsetAsync(counts, 0, (size_t)NN * 4, stream);
    k_hist<<<eB, 256, 0, stream>>>(col1, counts, flg);
    k_scan1<<<sB, 256, 0, stream>>>(counts, bsum);
    k_scan2<<<sB, 256, 0, stream>>>(counts, bsum, row_ptr, cursor);
    k_cscatter<<<eB, 256, 0, stream>>>(col0, col1, cursor, aux, node1, flg);

    // iteration 1: S from xb directly, fused MLP -> lgX (CSR-permuted)
    k_gath<<<nB4, 256, 0, stream>>>(xb, lgX, row_ptr, aux, S, 1);
    k_fused<<<gB, 256, 0, stream>>>(lgX, S, aux, node1, xb, b1, b2,
                                    Wf1, Wf2, lgX, flg, 1);
    // iteration 2 (lgX reads sequential in k_gath)
    k_gath<<<nB4, 256, 0, stream>>>(xb, lgX, row_ptr, aux, S, 2);
    k_fused<<<gB, 256, 0, stream>>>(lgX, S, aux, node1, xb, b1, b2,
                                    Wf1, Wf2, lgX, flg, 0);
    // scatter_mean back to nodes (sequential CSR read) + residual/relu
    LGNNGINELayer_12463995093126_kernel<<<nB4, 256, 0, stream>>>(
        x, lgX, row_ptr, d_out, flg);
}

// Round 18
// 344.983 us; speedup vs baseline: 1.2108x; 1.0041x over previous
//
#include <hip/hip_runtime.h>
#include <hip/hip_bf16.h>

constexpr int NN = 50000;
constexpr int EE = 200000;
typedef __bf16 bf16x8 __attribute__((ext_vector_type(8)));
typedef float f32x4 __attribute__((ext_vector_type(4)));

__device__ __forceinline__ float b2f(unsigned short s) {
    union { unsigned u; float f; } c; c.u = ((unsigned)s) << 16; return c.f;
}
// native RTNE f32->bf16 (compiler emits v_cvt_pk_bf16_f32 for pairs)
__device__ __forceinline__ unsigned short bfbits(float f) {
    union { __bf16 b; unsigned short u; } c; c.b = (__bf16)f; return c.u;
}
__device__ __forceinline__ unsigned pkbf(float lo, float hi) {
    return ((unsigned)bfbits(hi) << 16) | bfbits(lo);
}
__device__ __forceinline__ float xv(const void* p, long i, int f32m) {
    return f32m ? ((const float*)p)[i] : b2f(((const unsigned short*)p)[i]);
}
__device__ __forceinline__ int iv(const int* p, int i, int i64m) {
    return i64m ? p[2 * i] : p[i];
}

// parallel dtype sniff
__global__ void k_detect(const unsigned short* x16, const int* c32, int* flg) {
    __shared__ int sf, si;
    int t = threadIdx.x;
    if (t == 0) { sf = 0; si = 1; }
    __syncthreads();
    for (int i = t; i < 16384; i += 1024)
        if (((x16[i] >> 7) & 0xFF) == 0xFF) sf = 1;
    if (t < 64)
        if (c32[2 * t + 1] != 0) si = 0;
    __syncthreads();
    if (t == 0) { flg[0] = sf; flg[1] = si; }
}

// x -> bf16 image xb (all structural gathers read this; half the bytes of f32)
__global__ void k_cast(const void* x, unsigned short* xb, const int* flg) {
    int i = blockIdx.x * 256 + threadIdx.x;       // 8 elements per thread
    if (i >= NN * 16) return;
    if (flg[0]) {
        const float4* xp = (const float4*)x + (size_t)i * 2;
        float4 u = xp[0], v = xp[1];
        uint4 o;
        o.x = pkbf(u.x, u.y); o.y = pkbf(u.z, u.w);
        o.z = pkbf(v.x, v.y); o.w = pkbf(v.z, v.w);
        ((uint4*)xb)[i] = o;
    } else {
        ((uint4*)xb)[i] = ((const uint4*)x)[i];
    }
}

// Pack W1,W2 into bf16 MFMA B-fragment images in ONE dispatch (grid 16).
// chunk=(t*4+c)*64+l ; Wf[chunk*8+j] = W[c*32+(l>>4)*8+j][t*16+(l&15)]
__global__ void k_wfrag2(const void* W1, const void* W2,
                         unsigned short* Wf1, unsigned short* Wf2, const int* flg) {
    int f32m = flg[0];
    int g = blockIdx.x;
    const void* W = (g < 8) ? W1 : W2;
    unsigned short* Wf = (g < 8) ? Wf1 : Wf2;
    int chunk = (g & 7) * 256 + threadIdx.x;
    int l = chunk & 63, c = (chunk >> 6) & 3, t = chunk >> 8;
    int n = t * 16 + (l & 15), k0 = c * 32 + ((l >> 4) * 8);
    for (int j = 0; j < 8; j++) Wf[chunk * 8 + j] = bfbits(xv(W, (long)(k0 + j) * 128 + n, f32m));
}

// ---- CSR build (by col1), done once ----
__global__ void k_hist(const int* col1, int* counts, const int* flg) {
    int e = blockIdx.x * 256 + threadIdx.x;
    if (e >= EE) return;
    atomicAdd(&counts[iv(col1, e, flg[1])], 1);
}

// multi-block scan, stage 1: per-block sums (256 counts/block)
__global__ void k_scan1(const int* counts, int* bsum) {
    __shared__ int sh[256];
    int b = blockIdx.x, t = threadIdx.x;
    int idx = b * 256 + t;
    sh[t] = (idx < NN) ? counts[idx] : 0;
    __syncthreads();
    for (int off = 128; off > 0; off >>= 1) {
        if (t < off) sh[t] += sh[t + off];
        __syncthreads();
    }
    if (t == 0) bsum[b] = sh[0];
}

// stage 2: base = sum(bsum[0..b)), intra-block exclusive scan -> row_ptr/cursor
__global__ void k_scan2(const int* counts, const int* bsum,
                        int* row_ptr, int* cursor) {
    __shared__ int sh[256];
    __shared__ int base_s;
    int b = blockIdx.x, t = threadIdx.x;
    sh[t] = (t < b) ? bsum[t] : 0;
    __syncthreads();
    for (int off = 128; off > 0; off >>= 1) {
        if (t < off) sh[t] += sh[t + off];
        __syncthreads();
    }
    if (t == 0) base_s = sh[0];
    __syncthreads();
    int idx = b * 256 + t;
    int v = (idx < NN) ? counts[idx] : 0;
    sh[t] = v;
    __syncthreads();
    for (int off = 1; off < 256; off <<= 1) {
        int add = (t >= off) ? sh[t - off] : 0;
        __syncthreads();
        sh[t] += add;
        __syncthreads();
    }
    int ex = base_s + sh[t] - v;   // exclusive prefix
    if (idx < NN) { row_ptr[idx] = ex; cursor[idx] = ex; }
    if (idx == NN - 1) row_ptr[NN] = ex + v;
}

// position p (CSR slot under col1): aux[p] = col0[e] | selfloop<<31; node1[p] = col1[e].
// lgX is stored PERMUTED: edge e's features live at row p.
__global__ void k_cscatter(const int* col0, const int* col1, int* cursor,
                           unsigned* aux, int* node1, const int* flg) {
    int e = blockIdx.x * 256 + threadIdx.x;
    if (e >= EE) return;
    int i64m = flg[1];
    int a = iv(col0, e, i64m), b = iv(col1, e, i64m);
    int pos = atomicAdd(&cursor[b], 1);
    aux[pos] = (unsigned)a | (a == b ? 0x80000000u : 0u);
    node1[pos] = b;
}

// S[n][k] (bf16) = sum over non-self-loop in-edges of relu(msg).
//   mode 1: msg = 0.5*xb[col0] + 1.5*xb[n]   (bf16 gather, 256B rows)
//   mode 2: msg = lgX[p] + xb[n]             (SEQUENTIAL rows lo..hi)
// One wave per node; lane owns columns 2l,2l+1.
__global__ void k_gath(const unsigned short* xb, const unsigned short* lgX,
                       const int* row_ptr, const unsigned* aux,
                       unsigned short* S, int mode) {
    int n = blockIdx.x * 4 + (threadIdx.x >> 6);
    if (n >= NN) return;
    int l = threadIdx.x & 63, k0 = l * 2;
    int lo = row_ptr[n], hi = row_ptr[n + 1];
    unsigned un = *(const unsigned*)(xb + (size_t)n * 128 + k0);
    float xn0 = b2f((unsigned short)un), xn1 = b2f((unsigned short)(un >> 16));
    float a0 = 0.0f, a1 = 0.0f;
    if (mode == 1) {
        for (int p = lo; p < hi; p++) {
            unsigned av = aux[p];
            if (av & 0x80000000u) continue;
            unsigned u = *(const unsigned*)(xb + (size_t)av * 128 + k0);
            a0 += fmaxf(0.5f * b2f((unsigned short)u) + 1.5f * xn0, 0.0f);
            a1 += fmaxf(0.5f * b2f((unsigned short)(u >> 16)) + 1.5f * xn1, 0.0f);
        }
    } else {
        for (int p = lo; p < hi; p++) {
            if (aux[p] & 0x80000000u) continue;
            unsigned u = *(const unsigned*)(lgX + (size_t)p * 128 + k0);   // sequential
            a0 += fmaxf(b2f((unsigned short)u) + xn0, 0.0f);
            a1 += fmaxf(b2f((unsigned short)(u >> 16)) + xn1, 0.0f);
        }
    }
    *(unsigned*)(S + (size_t)n * 128 + k0) = pkbf(a0, a1);
}

// Fused 2-layer MLP: each wave owns 32 CSR positions (2 row-tiles, Wf-frag reuse
// r17) + the weight image STAGED IN LDS once per block (r18): Wf global traffic
// drops from per-wave to per-block (4x), and GEMM B-reads hit LDS. LDS is
// reloaded (Wf1 then Wf2) between GEMMs: 32KB Wfs + 32KB H regions = 64KB.
// Tail waves stay for barriers (no early return); loads clamp, stores guard.
__global__ __launch_bounds__(256, 2)
void k_fused(const unsigned short* A, const unsigned short* S,
             const unsigned* aux, const int* node1, const unsigned short* xb,
             const void* bias1, const void* bias2,
             const unsigned short* Wf1, const unsigned short* Wf2,
             unsigned short* Out, const int* flg, int initA) {
    __shared__ unsigned short Wfs[16384];  // 32 KB staged weight image
    __shared__ unsigned short Hl[16384];   // 32 KB: 4 waves x 8 KB
    int f32m = flg[0];
    int tid = threadIdx.x;
    int w = tid >> 6, l = tid & 63;
    int lq = l >> 4, ln = l & 15;
    int e0 = blockIdx.x * 128 + w * 32;    // wave's 32 positions
    bool active = e0 < EE;                 // whole-wave granular (EE % 32 == 0)
    unsigned short* W_ = Hl + w * 4096;    // wave-private 8 KB region

    // ---- issue Wf1 -> LDS (cooperative, 2048 uint4; overlaps A-staging below)
    for (int i = 0; i < 8; i++)
        ((uint4*)Wfs)[i * 256 + tid] = ((const uint4*)Wf1)[i * 256 + tid];

    // ---- stage A-frags IN REGISTERS for both row-tiles (clamped for tail)
    bf16x8 af[2][4];
    for (int t = 0; t < 2; t++) {
        int row = e0 + t * 16 + ln;
        if (row >= EE) row = EE - 1;       // harmless clamp (inactive waves)
        int aN = (int)(aux[row] & 0x7fffffffu);
        int bN = initA ? node1[row] : 0;
        for (int c = 0; c < 4; c++) {
            int k0 = c * 32 + lq * 8;
            uint4 svv = *(const uint4*)(S + (size_t)aN * 128 + k0);
            const unsigned short* sp = (const unsigned short*)&svv;
            if (initA) {
                uint4 xav = *(const uint4*)(xb + (size_t)aN * 128 + k0);
                uint4 xbv = *(const uint4*)(xb + (size_t)bN * 128 + k0);
                const unsigned short* xa = (const unsigned short*)&xav;
                const unsigned short* xc = (const unsigned short*)&xbv;
                for (int j = 0; j < 8; j++)
                    af[t][c][j] = (__bf16)(0.5f * (b2f(xa[j]) + b2f(xc[j])) + b2f(sp[j]));
            } else {
                uint4 av = *(const uint4*)(A + (size_t)row * 128 + k0);
                const unsigned short* ap = (const unsigned short*)&av;
                for (int j = 0; j < 8; j++)
                    af[t][c][j] = (__bf16)(b2f(ap[j]) + b2f(sp[j]));
            }
        }
    }

    __syncthreads();   // Wf1 image ready in LDS

    // ---- GEMM1: 32 rows x 128 cols; B-frags from LDS, each feeds 2 MFMAs
    f32x4 acc[2][8];
    for (int t = 0; t < 2; t++)
        for (int j = 0; j < 8; j++)
            for (int r = 0; r < 4; r++) acc[t][j][r] = 0.0f;
    for (int c = 0; c < 4; c++) {
        for (int j = 0; j < 8; j++) {
            bf16x8 bf = *(const bf16x8*)(Wfs + (((j * 4 + c) * 64 + l) * 8));
            acc[0][j] = __builtin_amdgcn_mfma_f32_16x16x32_bf16(af[0][c], bf, acc[0][j], 0, 0, 0);
            acc[1][j] = __builtin_amdgcn_mfma_f32_16x16x32_bf16(af[1][c], bf, acc[1][j], 0, 0, 0);
        }
    }

    __syncthreads();   // all GEMM1 reads of Wfs complete

    // ---- issue Wf2 -> LDS; H-transpose (independent region) overlaps the loads
    for (int i = 0; i < 8; i++)
        ((uint4*)Wfs)[i * 256 + tid] = ((const uint4*)Wf2)[i * 256 + tid];
    for (int t = 0; t < 2; t++) {
        for (int j = 0; j < 8; j++) {
            int n = j * 16 + ln;
            float bv = xv(bias1, n, f32m);
            int c2 = n >> 5, lhi = ((n >> 3) & 3) * 16, j2 = n & 7;
            for (int rg = 0; rg < 4; rg++) {
                float h = fmaxf(acc[t][j][rg] + bv, 0.0f);
                W_[t * 2048 + (c2 * 64 + lhi + lq * 4 + rg) * 8 + j2] = bfbits(h);
            }
        }
    }

    __syncthreads();   // Wf2 image ready

    // ---- GEMM2: A from own H region (same-wave in-order), B from LDS
    for (int t = 0; t < 2; t++)
        for (int j = 0; j < 8; j++)
            for (int r = 0; r < 4; r++) acc[t][j][r] = 0.0f;
    for (int c = 0; c < 4; c++) {
        bf16x8 a20 = *(const bf16x8*)(W_ + (c * 64 + l) * 8);
        bf16x8 a21 = *(const bf16x8*)(W_ + 2048 + (c * 64 + l) * 8);
        for (int j = 0; j < 8; j++) {
            bf16x8 bf = *(const bf16x8*)(Wfs + (((j * 4 + c) * 64 + l) * 8));
            acc[0][j] = __builtin_amdgcn_mfma_f32_16x16x32_bf16(a20, bf, acc[0][j], 0, 0, 0);
            acc[1][j] = __builtin_amdgcn_mfma_f32_16x16x32_bf16(a21, bf, acc[1][j], 0, 0, 0);
        }
    }

    // ---- C2 + b2 -> row-major in region, then coalesced store (active only)
    for (int t = 0; t < 2; t++) {
        for (int j = 0; j < 8; j++) {
            int n = j * 16 + ln;
            float bv = xv(bias2, n, f32m);
            for (int rg = 0; rg < 4; rg++)
                W_[t * 2048 + (lq * 4 + rg) * 128 + n] = bfbits(acc[t][j][rg] + bv);
        }
    }
    if (active) {
        for (int i = 0; i < 8; i++) {
            int idx = i * 64 + l;    // 512 uint4 = 32 rows x 256B
            ((uint4*)Out)[(size_t)e0 * 16 + idx] = ((const uint4*)W_)[idx];
        }
    }
}

// out[n] = x[n] + relu(mean over ALL in-edges of lgX rows lo..hi) (0 if deg==0).
// Fully sequential reads; residual uses original-precision x.
__global__ void LGNNGINELayer_12463995093126_kernel(
    const void* x, const unsigned short* lgX, const int* row_ptr,
    void* out, const int* flg) {
    int n = blockIdx.x * 4 + (threadIdx.x >> 6);
    if (n >= NN) return;
    int l = threadIdx.x & 63, k0 = l * 2;
    int f32m = flg[0];
    int lo = row_ptr[n], hi = row_ptr[n + 1];
    float a0 = 0.0f, a1 = 0.0f;
    for (int p = lo; p < hi; p++) {
        unsigned u = *(const unsigned*)(lgX + (size_t)p * 128 + k0);
        a0 += b2f((unsigned short)u);
        a1 += b2f((unsigned short)(u >> 16));
    }
    float g0 = 0.0f, g1 = 0.0f;
    if (hi > lo) {
        float inv = 1.0f / (float)(hi - lo);
        g0 = fmaxf(a0 * inv, 0.0f);
        g1 = fmaxf(a1 * inv, 0.0f);
    }
    if (f32m) {
        ((float*)out)[(long)n * 128 + k0]     = ((const float*)x)[(long)n * 128 + k0] + g0;
        ((float*)out)[(long)n * 128 + k0 + 1] = ((const float*)x)[(long)n * 128 + k0 + 1] + g1;
    } else {
        unsigned u = *(const unsigned*)((const unsigned short*)x + (long)n * 128 + k0);
        float r0 = b2f((unsigned short)u) + g0;
        float r1 = b2f((unsigned short)(u >> 16)) + g1;
        *(unsigned*)((unsigned short*)out + (long)n * 128 + k0) = pkbf(r0, r1);
    }
}

extern "C" void kernel_launch(void* const* d_in, const int* in_sizes, int n_in,
                              void* d_out, int out_size, void* d_ws, size_t ws_size,
                              hipStream_t stream) {
    (void)in_sizes; (void)n_in; (void)out_size; (void)ws_size;
    const void* x = d_in[0];
    const void* W1 = d_in[1];
    const void* b1 = d_in[2];
    const void* W2 = d_in[3];
    const void* b2 = d_in[4];
    const int* col0 = (const int*)d_in[5];
    const int* col1 = (const int*)d_in[6];

    // ws: lgX(csr) | S | xb | row_ptr | cursor | counts | bsum | aux | node1 | flg | Wf1 | Wf2
    char* p = (char*)d_ws;
    unsigned short* lgX = (unsigned short*)p; p += (size_t)EE * 128 * 2;
    unsigned short* S = (unsigned short*)p;   p += (size_t)NN * 128 * 2;
    unsigned short* xb = (unsigned short*)p;  p += (size_t)NN * 128 * 2;
    int* row_ptr = (int*)p;                   p += (size_t)(NN + 16) * 4;
    int* cursor = (int*)p;                    p += (size_t)NN * 4;
    int* counts = (int*)p;                    p += (size_t)NN * 4;
    int* bsum = (int*)p;                      p += 256 * 4;
    unsigned* aux = (unsigned*)p;             p += (size_t)EE * 4;
    int* node1 = (int*)p;                     p += (size_t)EE * 4;
    int* flg = (int*)p;                       p += 256;
    unsigned short* Wf1 = (unsigned short*)p; p += 16384 * 2;
    unsigned short* Wf2 = (unsigned short*)p;

    int gB = (EE + 127) / 128;         // 1563 blocks, wave = 32 positions
    int eB = (EE + 255) / 256;
    int nB4 = (NN + 3) / 4;
    int sB = (NN + 255) / 256;         // 196 scan blocks
    int cB = (NN * 16 + 255) / 256;    // cast blocks

    k_detect<<<1, 1024, 0, stream>>>((const unsigned short*)x, col0, flg);
    k_cast<<<cB, 256, 0, stream>>>(x, xb, flg);
    k_wfrag2<<<16, 256, 0, stream>>>(W1, W2, Wf1, Wf2, flg);

    // CSR by col1 (col1 fixed across iterations)
    (void)hipMemsetAsync(counts, 0, (size_t)NN * 4, stream);
    k_hist<<<eB, 256, 0, stream>>>(col1, counts, flg);
    k_scan1<<<sB, 256, 0, stream>>>(counts, bsum);
    k_scan2<<<sB, 256, 0, stream>>>(counts, bsum, row_ptr, cursor);
    k_cscatter<<<eB, 256, 0, stream>>>(col0, col1, cursor, aux, node1, flg);

    // iteration 1: S from xb directly, fused MLP -> lgX (CSR-permuted)
    k_gath<<<nB4, 256, 0, stream>>>(xb, lgX, row_ptr, aux, S, 1);
    k_fused<<<gB, 256, 0, stream>>>(lgX, S, aux, node1, xb, b1, b2,
                                    Wf1, Wf2, lgX, flg, 1);
    // iteration 2 (lgX reads sequential in k_gath)
    k_gath<<<nB4, 256, 0, stream>>>(xb, lgX, row_ptr, aux, S, 2);
    k_fused<<<gB, 256, 0, stream>>>(lgX, S, aux, node1, xb, b1, b2,
                                    Wf1, Wf2, lgX, flg, 0);
    // scatter_mean back to nodes (sequential CSR read) + residual/relu
    LGNNGINELayer_12463995093126_kernel<<<nB4, 256, 0, stream>>>(
        x, lgX, row_ptr, d_out, flg);
}

// Round 19
// 325.466 us; speedup vs baseline: 1.2834x; 1.0600x over previous
//
#include <hip/hip_runtime.h>
#include <hip/hip_bf16.h>

constexpr int NN = 50000;
constexpr int EE = 200000;
typedef __bf16 bf16x8 __attribute__((ext_vector_type(8)));
typedef float f32x4 __attribute__((ext_vector_type(4)));

__device__ __forceinline__ float b2f(unsigned short s) {
    union { unsigned u; float f; } c; c.u = ((unsigned)s) << 16; return c.f;
}
// native RTNE f32->bf16 (compiler emits v_cvt_pk_bf16_f32 for pairs)
__device__ __forceinline__ unsigned short bfbits(float f) {
    union { __bf16 b; unsigned short u; } c; c.b = (__bf16)f; return c.u;
}
__device__ __forceinline__ unsigned pkbf(float lo, float hi) {
    return ((unsigned)bfbits(hi) << 16) | bfbits(lo);
}
__device__ __forceinline__ float xv(const void* p, long i, int f32m) {
    return f32m ? ((const float*)p)[i] : b2f(((const unsigned short*)p)[i]);
}
__device__ __forceinline__ int iv(const int* p, int i, int i64m) {
    return i64m ? p[2 * i] : p[i];
}

// parallel dtype sniff
__global__ void k_detect(const unsigned short* x16, const int* c32, int* flg) {
    __shared__ int sf, si;
    int t = threadIdx.x;
    if (t == 0) { sf = 0; si = 1; }
    __syncthreads();
    for (int i = t; i < 16384; i += 1024)
        if (((x16[i] >> 7) & 0xFF) == 0xFF) sf = 1;
    if (t < 64)
        if (c32[2 * t + 1] != 0) si = 0;
    __syncthreads();
    if (t == 0) { flg[0] = sf; flg[1] = si; }
}

// x -> bf16 image xb (all structural gathers read this; half the bytes of f32)
__global__ void k_cast(const void* x, unsigned short* xb, const int* flg) {
    int i = blockIdx.x * 256 + threadIdx.x;       // 8 elements per thread
    if (i >= NN * 16) return;
    if (flg[0]) {
        const float4* xp = (const float4*)x + (size_t)i * 2;
        float4 u = xp[0], v = xp[1];
        uint4 o;
        o.x = pkbf(u.x, u.y); o.y = pkbf(u.z, u.w);
        o.z = pkbf(v.x, v.y); o.w = pkbf(v.z, v.w);
        ((uint4*)xb)[i] = o;
    } else {
        ((uint4*)xb)[i] = ((const uint4*)x)[i];
    }
}

// Pack W1,W2 into bf16 MFMA B-fragment images in ONE dispatch (grid 16).
// chunk=(t*4+c)*64+l ; Wf[chunk*8+j] = W[c*32+(l>>4)*8+j][t*16+(l&15)]
__global__ void k_wfrag2(const void* W1, const void* W2,
                         unsigned short* Wf1, unsigned short* Wf2, const int* flg) {
    int f32m = flg[0];
    int g = blockIdx.x;
    const void* W = (g < 8) ? W1 : W2;
    unsigned short* Wf = (g < 8) ? Wf1 : Wf2;
    int chunk = (g & 7) * 256 + threadIdx.x;
    int l = chunk & 63, c = (chunk >> 6) & 3, t = chunk >> 8;
    int n = t * 16 + (l & 15), k0 = c * 32 + ((l >> 4) * 8);
    for (int j = 0; j < 8; j++) Wf[chunk * 8 + j] = bfbits(xv(W, (long)(k0 + j) * 128 + n, f32m));
}

// ---- CSR build (by col1), done once ----
__global__ void k_hist(const int* col1, int* counts, const int* flg) {
    int e = blockIdx.x * 256 + threadIdx.x;
    if (e >= EE) return;
    atomicAdd(&counts[iv(col1, e, flg[1])], 1);
}

// multi-block scan, stage 1: per-block sums (256 counts/block)
__global__ void k_scan1(const int* counts, int* bsum) {
    __shared__ int sh[256];
    int b = blockIdx.x, t = threadIdx.x;
    int idx = b * 256 + t;
    sh[t] = (idx < NN) ? counts[idx] : 0;
    __syncthreads();
    for (int off = 128; off > 0; off >>= 1) {
        if (t < off) sh[t] += sh[t + off];
        __syncthreads();
    }
    if (t == 0) bsum[b] = sh[0];
}

// stage 2: base = sum(bsum[0..b)), intra-block exclusive scan -> row_ptr/cursor
__global__ void k_scan2(const int* counts, const int* bsum,
                        int* row_ptr, int* cursor) {
    __shared__ int sh[256];
    __shared__ int base_s;
    int b = blockIdx.x, t = threadIdx.x;
    sh[t] = (t < b) ? bsum[t] : 0;
    __syncthreads();
    for (int off = 128; off > 0; off >>= 1) {
        if (t < off) sh[t] += sh[t + off];
        __syncthreads();
    }
    if (t == 0) base_s = sh[0];
    __syncthreads();
    int idx = b * 256 + t;
    int v = (idx < NN) ? counts[idx] : 0;
    sh[t] = v;
    __syncthreads();
    for (int off = 1; off < 256; off <<= 1) {
        int add = (t >= off) ? sh[t - off] : 0;
        __syncthreads();
        sh[t] += add;
        __syncthreads();
    }
    int ex = base_s + sh[t] - v;   // exclusive prefix
    if (idx < NN) { row_ptr[idx] = ex; cursor[idx] = ex; }
    if (idx == NN - 1) row_ptr[NN] = ex + v;
}

// position p (CSR slot under col1): aux[p] = col0[e] | selfloop<<31; node1[p] = col1[e].
// lgX is stored PERMUTED: edge e's features live at row p.
__global__ void k_cscatter(const int* col0, const int* col1, int* cursor,
                           unsigned* aux, int* node1, const int* flg) {
    int e = blockIdx.x * 256 + threadIdx.x;
    if (e >= EE) return;
    int i64m = flg[1];
    int a = iv(col0, e, i64m), b = iv(col1, e, i64m);
    int pos = atomicAdd(&cursor[b], 1);
    aux[pos] = (unsigned)a | (a == b ? 0x80000000u : 0u);
    node1[pos] = b;
}

// S[n][k] (bf16) = sum over non-self-loop in-edges of relu(msg).
//   mode 1: msg = 0.5*xb[col0] + 1.5*xb[n]   (bf16 gather, 256B rows)
//   mode 2: msg = lgX[p] + xb[n]             (SEQUENTIAL rows lo..hi)
// One wave per node; lane owns columns 2l,2l+1.
__global__ void k_gath(const unsigned short* xb, const unsigned short* lgX,
                       const int* row_ptr, const unsigned* aux,
                       unsigned short* S, int mode) {
    int n = blockIdx.x * 4 + (threadIdx.x >> 6);
    if (n >= NN) return;
    int l = threadIdx.x & 63, k0 = l * 2;
    int lo = row_ptr[n], hi = row_ptr[n + 1];
    unsigned un = *(const unsigned*)(xb + (size_t)n * 128 + k0);
    float xn0 = b2f((unsigned short)un), xn1 = b2f((unsigned short)(un >> 16));
    float a0 = 0.0f, a1 = 0.0f;
    if (mode == 1) {
        for (int p = lo; p < hi; p++) {
            unsigned av = aux[p];
            if (av & 0x80000000u) continue;
            unsigned u = *(const unsigned*)(xb + (size_t)av * 128 + k0);
            a0 += fmaxf(0.5f * b2f((unsigned short)u) + 1.5f * xn0, 0.0f);
            a1 += fmaxf(0.5f * b2f((unsigned short)(u >> 16)) + 1.5f * xn1, 0.0f);
        }
    } else {
        for (int p = lo; p < hi; p++) {
            if (aux[p] & 0x80000000u) continue;
            unsigned u = *(const unsigned*)(lgX + (size_t)p * 128 + k0);   // sequential
            a0 += fmaxf(b2f((unsigned short)u) + xn0, 0.0f);
            a1 += fmaxf(b2f((unsigned short)(u >> 16)) + xn1, 0.0f);
        }
    }
    *(unsigned*)(S + (size_t)n * 128 + k0) = pkbf(a0, a1);
}

// Fused 2-layer MLP: wave = 32 CSR positions (2 row-tiles, Wf-frag 2x reuse).
// ONE 32KB LDS buffer, time-shared: Wf1 image (staged per block) for GEMM1,
// then repurposed as per-wave H/C2 regions; GEMM2 reads B from global Wf2
// (L2-resident, 2x reuse per load). 32KB LDS + ~88 VGPR -> 4 blocks/CU
// (vs r18's 2), restoring the latency-hiding the 64KB version lost.
// Tail waves participate in barriers (no early return); loads clamp, stores guard.
__global__ __launch_bounds__(256, 4)
void k_fused(const unsigned short* A, const unsigned short* S,
             const unsigned* aux, const int* node1, const unsigned short* xb,
             const void* bias1, const void* bias2,
             const unsigned short* Wf1, const unsigned short* Wf2,
             unsigned short* Out, const int* flg, int initA) {
    __shared__ unsigned short Wfs[16384];  // 32 KB: Wf1 image, then 4x8KB H/C2
    int f32m = flg[0];
    int tid = threadIdx.x;
    int w = tid >> 6, l = tid & 63;
    int lq = l >> 4, ln = l & 15;
    int e0 = blockIdx.x * 128 + w * 32;    // wave's 32 positions
    bool active = e0 < EE;                 // whole-wave granular (EE % 32 == 0)
    unsigned short* W_ = Wfs + w * 4096;   // wave-private 8 KB (post-repurpose)

    // ---- issue Wf1 -> LDS (cooperative; overlaps A-staging below)
    for (int i = 0; i < 8; i++)
        ((uint4*)Wfs)[i * 256 + tid] = ((const uint4*)Wf1)[i * 256 + tid];

    // ---- stage A-frags IN REGISTERS for both row-tiles (clamped for tail)
    bf16x8 af[2][4];
    for (int t = 0; t < 2; t++) {
        int row = e0 + t * 16 + ln;
        if (row >= EE) row = EE - 1;       // harmless clamp (inactive waves)
        int aN = (int)(aux[row] & 0x7fffffffu);
        int bN = initA ? node1[row] : 0;
        for (int c = 0; c < 4; c++) {
            int k0 = c * 32 + lq * 8;
            uint4 svv = *(const uint4*)(S + (size_t)aN * 128 + k0);
            const unsigned short* sp = (const unsigned short*)&svv;
            if (initA) {
                uint4 xav = *(const uint4*)(xb + (size_t)aN * 128 + k0);
                uint4 xbv = *(const uint4*)(xb + (size_t)bN * 128 + k0);
                const unsigned short* xa = (const unsigned short*)&xav;
                const unsigned short* xc = (const unsigned short*)&xbv;
                for (int j = 0; j < 8; j++)
                    af[t][c][j] = (__bf16)(0.5f * (b2f(xa[j]) + b2f(xc[j])) + b2f(sp[j]));
            } else {
                uint4 av = *(const uint4*)(A + (size_t)row * 128 + k0);
                const unsigned short* ap = (const unsigned short*)&av;
                for (int j = 0; j < 8; j++)
                    af[t][c][j] = (__bf16)(b2f(ap[j]) + b2f(sp[j]));
            }
        }
    }

    __syncthreads();   // Wf1 image ready in LDS

    // ---- GEMM1: 32 rows x 128 cols; B-frags from LDS, each feeds 2 MFMAs
    f32x4 acc[2][8];
    for (int t = 0; t < 2; t++)
        for (int j = 0; j < 8; j++)
            for (int r = 0; r < 4; r++) acc[t][j][r] = 0.0f;
    for (int c = 0; c < 4; c++) {
        for (int j = 0; j < 8; j++) {
            bf16x8 bf = *(const bf16x8*)(Wfs + (((j * 4 + c) * 64 + l) * 8));
            acc[0][j] = __builtin_amdgcn_mfma_f32_16x16x32_bf16(af[0][c], bf, acc[0][j], 0, 0, 0);
            acc[1][j] = __builtin_amdgcn_mfma_f32_16x16x32_bf16(af[1][c], bf, acc[1][j], 0, 0, 0);
        }
    }

    __syncthreads();   // ALL waves' GEMM1 reads of Wf1 image complete

    // ---- H = relu(C1+b1) -> own 8KB sub-region of the SAME buffer
    for (int t = 0; t < 2; t++) {
        for (int j = 0; j < 8; j++) {
            int n = j * 16 + ln;
            float bv = xv(bias1, n, f32m);
            int c2 = n >> 5, lhi = ((n >> 3) & 3) * 16, j2 = n & 7;
            for (int rg = 0; rg < 4; rg++) {
                float h = fmaxf(acc[t][j][rg] + bv, 0.0f);
                W_[t * 2048 + (c2 * 64 + lhi + lq * 4 + rg) * 8 + j2] = bfbits(h);
            }
        }
    }

    // ---- GEMM2: A from own H region (same-wave, in-order); B from GLOBAL Wf2
    // (L2-resident; each load feeds 2 MFMAs)
    for (int t = 0; t < 2; t++)
        for (int j = 0; j < 8; j++)
            for (int r = 0; r < 4; r++) acc[t][j][r] = 0.0f;
    for (int c = 0; c < 4; c++) {
        bf16x8 a20 = *(const bf16x8*)(W_ + (c * 64 + l) * 8);
        bf16x8 a21 = *(const bf16x8*)(W_ + 2048 + (c * 64 + l) * 8);
        for (int j = 0; j < 8; j++) {
            bf16x8 bf = *(const bf16x8*)(Wf2 + (size_t)(((j * 4 + c) * 64 + l) * 8));
            acc[0][j] = __builtin_amdgcn_mfma_f32_16x16x32_bf16(a20, bf, acc[0][j], 0, 0, 0);
            acc[1][j] = __builtin_amdgcn_mfma_f32_16x16x32_bf16(a21, bf, acc[1][j], 0, 0, 0);
        }
    }

    // ---- C2 + b2 -> row-major in own region, then coalesced store (active only)
    for (int t = 0; t < 2; t++) {
        for (int j = 0; j < 8; j++) {
            int n = j * 16 + ln;
            float bv = xv(bias2, n, f32m);
            for (int rg = 0; rg < 4; rg++)
                W_[t * 2048 + (lq * 4 + rg) * 128 + n] = bfbits(acc[t][j][rg] + bv);
        }
    }
    if (active) {
        for (int i = 0; i < 8; i++) {
            int idx = i * 64 + l;    // 512 uint4 = 32 rows x 256B
            ((uint4*)Out)[(size_t)e0 * 16 + idx] = ((const uint4*)W_)[idx];
        }
    }
}

// out[n] = x[n] + relu(mean over ALL in-edges of lgX rows lo..hi) (0 if deg==0).
// Fully sequential reads; residual uses original-precision x.
__global__ void LGNNGINELayer_12463995093126_kernel(
    const void* x, const unsigned short* lgX, const int* row_ptr,
    void* out, const int* flg) {
    int n = blockIdx.x * 4 + (threadIdx.x >> 6);
    if (n >= NN) return;
    int l = threadIdx.x & 63, k0 = l * 2;
    int f32m = flg[0];
    int lo = row_ptr[n], hi = row_ptr[n + 1];
    float a0 = 0.0f, a1 = 0.0f;
    for (int p = lo; p < hi; p++) {
        unsigned u = *(const unsigned*)(lgX + (size_t)p * 128 + k0);
        a0 += b2f((unsigned short)u);
        a1 += b2f((unsigned short)(u >> 16));
    }
    float g0 = 0.0f, g1 = 0.0f;
    if (hi > lo) {
        float inv = 1.0f / (float)(hi - lo);
        g0 = fmaxf(a0 * inv, 0.0f);
        g1 = fmaxf(a1 * inv, 0.0f);
    }
    if (f32m) {
        ((float*)out)[(long)n * 128 + k0]     = ((const float*)x)[(long)n * 128 + k0] + g0;
        ((float*)out)[(long)n * 128 + k0 + 1] = ((const float*)x)[(long)n * 128 + k0 + 1] + g1;
    } else {
        unsigned u = *(const unsigned*)((const unsigned short*)x + (long)n * 128 + k0);
        float r0 = b2f((unsigned short)u) + g0;
        float r1 = b2f((unsigned short)(u >> 16)) + g1;
        *(unsigned*)((unsigned short*)out + (long)n * 128 + k0) = pkbf(r0, r1);
    }
}

extern "C" void kernel_launch(void* const* d_in, const int* in_sizes, int n_in,
                              void* d_out, int out_size, void* d_ws, size_t ws_size,
                              hipStream_t stream) {
    (void)in_sizes; (void)n_in; (void)out_size; (void)ws_size;
    const void* x = d_in[0];
    const void* W1 = d_in[1];
    const void* b1 = d_in[2];
    const void* W2 = d_in[3];
    const void* b2 = d_in[4];
    const int* col0 = (const int*)d_in[5];
    const int* col1 = (const int*)d_in[6];

    // ws: lgX(csr) | S | xb | row_ptr | cursor | counts | bsum | aux | node1 | flg | Wf1 | Wf2
    char* p = (char*)d_ws;
    unsigned short* lgX = (unsigned short*)p; p += (size_t)EE * 128 * 2;
    unsigned short* S = (unsigned short*)p;   p += (size_t)NN * 128 * 2;
    unsigned short* xb = (unsigned short*)p;  p += (size_t)NN * 128 * 2;
    int* row_ptr = (int*)p;                   p += (size_t)(NN + 16) * 4;
    int* cursor = (int*)p;                    p += (size_t)NN * 4;
    int* counts = (int*)p;                    p += (size_t)NN * 4;
    int* bsum = (int*)p;                      p += 256 * 4;
    unsigned* aux = (unsigned*)p;             p += (size_t)EE * 4;
    int* node1 = (int*)p;                     p += (size_t)EE * 4;
    int* flg = (int*)p;                       p += 256;
    unsigned short* Wf1 = (unsigned short*)p; p += 16384 * 2;
    unsigned short* Wf2 = (unsigned short*)p;

    int gB = (EE + 127) / 128;         // 1563 blocks, wave = 32 positions
    int eB = (EE + 255) / 256;
    int nB4 = (NN + 3) / 4;
    int sB = (NN + 255) / 256;         // 196 scan blocks
    int cB = (NN * 16 + 255) / 256;    // cast blocks

    k_detect<<<1, 1024, 0, stream>>>((const unsigned short*)x, col0, flg);
    k_cast<<<cB, 256, 0, stream>>>(x, xb, flg);
    k_wfrag2<<<16, 256, 0, stream>>>(W1, W2, Wf1, Wf2, flg);

    // CSR by col1 (col1 fixed across iterations)
    (void)hipMemsetAsync(counts, 0, (size_t)NN * 4, stream);
    k_hist<<<eB, 256, 0, stream>>>(col1, counts, flg);
    k_scan1<<<sB, 256, 0, stream>>>(counts, bsum);
    k_scan2<<<sB, 256, 0, stream>>>(counts, bsum, row_ptr, cursor);
    k_cscatter<<<eB, 256, 0, stream>>>(col0, col1, cursor, aux, node1, flg);

    // iteration 1: S from xb directly, fused MLP -> lgX (CSR-permuted)
    k_gath<<<nB4, 256, 0, stream>>>(xb, lgX, row_ptr, aux, S, 1);
    k_fused<<<gB, 256, 0, stream>>>(lgX, S, aux, node1, xb, b1, b2,
                                    Wf1, Wf2, lgX, flg, 1);
    // iteration 2 (lgX reads sequential in k_gath)
    k_gath<<<nB4, 256, 0, stream>>>(xb, lgX, row_ptr, aux, S, 2);
    k_fused<<<gB, 256, 0, stream>>>(lgX, S, aux, node1, xb, b1, b2,
                                    Wf1, Wf2, lgX, flg, 0);
    // scatter_mean back to nodes (sequential CSR read) + residual/relu
    LGNNGINELayer_12463995093126_kernel<<<nB4, 256, 0, stream>>>(
        x, lgX, row_ptr, d_out, flg);
}